// Round 6
// baseline (247.382 us; speedup 1.0000x reference)
//
#include <hip/hip_runtime.h>
#include <stdint.h>

#define B_ 2
#define S_ 2048
#define DM_ 2048
#define H_ 32
#define KVH_ 8
#define HD_ 64
#define NQK_ 3072   // 2048 q + 512 k + 512 v

typedef unsigned short u16;
typedef unsigned int u32;
typedef __attribute__((ext_vector_type(8))) short bf16x8;
typedef __attribute__((ext_vector_type(4))) float f32x4;
typedef __attribute__((ext_vector_type(16))) float f32x16;
typedef __attribute__((ext_vector_type(4))) u32 u32x4;

static __device__ __forceinline__ u16 f2bf(float f) {
  unsigned int u = __float_as_uint(f);
  u = (u + 0x7fffu + ((u >> 16) & 1u)) >> 16;
  return (u16)u;
}
static __device__ __forceinline__ float bf2f(u16 v) {
  unsigned int u = ((unsigned int)v) << 16;
  return __uint_as_float(u);
}

// global -> LDS direct (width 16). LDS dest = wave-uniform base + lane*16.
static __device__ __forceinline__ void gload16(const void* g, void* lds_wave_base) {
  __builtin_amdgcn_global_load_lds(
      (__attribute__((address_space(1))) unsigned int*)(uintptr_t)g,
      (__attribute__((address_space(3))) unsigned int*)(uintptr_t)lds_wave_base,
      16, 0, 0);
}

// ---------------- fp32 -> bf16 convert ----------------
__global__ void cvt_bf16(const float* __restrict__ in, u16* __restrict__ out, int n4) {
  int i = blockIdx.x * blockDim.x + threadIdx.x;
  if (i >= n4) return;
  const float4 v = ((const float4*)in)[i];
  ushort4 o;
  o.x = f2bf(v.x); o.y = f2bf(v.y); o.z = f2bf(v.z); o.w = f2bf(v.w);
  ((ushort4*)out)[i] = o;
}

// ---------------- GEMM: C(MxN) = A(MxK) * B(NxK)^T, bf16 in ----------------
#define BM 128
#define BN 128
#define BK 32

#define GEMM_BODY(CSTORE)                                                       \
  __shared__ u16 As[2][BM * BK];                                                \
  __shared__ u16 Bs[2][BN * BK];                                                \
  const int t = threadIdx.x;                                                    \
  const int lane = t & 63;                                                      \
  const int w = t >> 6;                                                         \
  const int wr = (w >> 1) * 64, wc = (w & 1) * 64;                              \
  const int m0 = blockIdx.y * BM;                                               \
  const int n0 = blockIdx.x * BN;                                               \
  f32x4 acc[4][4] = {};                                                         \
  const char* Ab = (const char*)A;                                              \
  const char* Bb = (const char*)Bw;                                             \
  const size_t K2 = (size_t)K * 2;                                              \
  const int P0 = t * 16;                                                        \
  const int row0 = P0 >> 6, kb0 = P0 & 63;                                      \
  const int P1 = 4096 + t * 16;                                                 \
  const int row1 = P1 >> 6, kb1 = P1 & 63;                                      \
  const int Pb0 = (w << 10), Pb1 = 4096 + (w << 10);                            \
  auto STAGE = [&](int buf, int k0) {                                           \
    gload16(Ab + (size_t)(m0 + row0) * K2 + (size_t)k0 * 2 + kb0, (char*)As[buf] + Pb0); \
    gload16(Ab + (size_t)(m0 + row1) * K2 + (size_t)k0 * 2 + kb1, (char*)As[buf] + Pb1); \
    gload16(Bb + (size_t)(n0 + row0) * K2 + (size_t)k0 * 2 + kb0, (char*)Bs[buf] + Pb0); \
    gload16(Bb + (size_t)(n0 + row1) * K2 + (size_t)k0 * 2 + kb1, (char*)Bs[buf] + Pb1); \
  };                                                                            \
  STAGE(0, 0);                                                                  \
  __syncthreads();                                                              \
  int cur = 0;                                                                  \
  for (int k0 = 0; k0 < K; k0 += BK) {                                          \
    if (k0 + BK < K) STAGE(cur ^ 1, k0 + BK);                                   \
    bf16x8 af[4], bfr[4];                                                       \
    _Pragma("unroll")                                                           \
    for (int m = 0; m < 4; m++)                                                 \
      af[m] = *(const bf16x8*)((const char*)As[cur] +                           \
               (wr + m * 16 + (lane & 15)) * 64 + ((lane >> 4) << 4));          \
    _Pragma("unroll")                                                           \
    for (int n = 0; n < 4; n++)                                                 \
      bfr[n] = *(const bf16x8*)((const char*)Bs[cur] +                          \
               (wc + n * 16 + (lane & 15)) * 64 + ((lane >> 4) << 4));          \
    _Pragma("unroll")                                                           \
    for (int m = 0; m < 4; m++)                                                 \
      _Pragma("unroll")                                                         \
      for (int n = 0; n < 4; n++)                                               \
        acc[m][n] = __builtin_amdgcn_mfma_f32_16x16x32_bf16(af[m], bfr[n], acc[m][n], 0, 0, 0); \
    __syncthreads();                                                            \
    cur ^= 1;                                                                   \
  }                                                                             \
  _Pragma("unroll")                                                             \
  for (int m = 0; m < 4; m++) {                                                 \
    const int r0 = m0 + wr + m * 16 + ((lane >> 4) << 2);                       \
    _Pragma("unroll")                                                           \
    for (int n = 0; n < 4; n++) {                                               \
      const int c = n0 + wc + n * 16 + (lane & 15);                             \
      _Pragma("unroll")                                                         \
      for (int j = 0; j < 4; j++) CSTORE;                                       \
    }                                                                           \
  }

__global__ __launch_bounds__(256) void gemm_bt(const u16* __restrict__ A,
                                               const u16* __restrict__ Bw,
                                               float* __restrict__ C,
                                               int M, int N, int K) {
  GEMM_BODY(C[(size_t)(r0 + j) * N + c] = acc[m][n][j])
}

__global__ __launch_bounds__(256) void gemm_btb(const u16* __restrict__ A,
                                                const u16* __restrict__ Bw,
                                                u16* __restrict__ C,
                                                int M, int N, int K) {
  GEMM_BODY(C[(size_t)(r0 + j) * N + c] = f2bf(acc[m][n][j]))
}

// ------- fused RMSNorm + RoPE, in-place on bf16 QKV buffer ------------------
__global__ void norm_rope_inplace(u16* __restrict__ QKV, const float* __restrict__ cosT,
                                  const float* __restrict__ sinT,
                                  const float* __restrict__ qw,
                                  const float* __restrict__ kw, float qscale) {
  const int r = blockIdx.x * 4 + (threadIdx.x >> 6);
  const int lane = threadIdx.x & 63;
  const int hh2 = r % 40;
  const int bs = r / 40;
  const int s = bs & (S_ - 1);
  const bool isq = hh2 < 32;
  u16* p = QKV + (size_t)bs * NQK_ + hh2 * 64 + lane;
  float x = bf2f(*p);
  float ss = x * x;
#pragma unroll
  for (int m = 1; m < 64; m <<= 1) ss += __shfl_xor(ss, m, 64);
  const float wgt = isq ? qw[lane] : kw[lane];
  float xn = x * rsqrtf(ss * (1.0f / 64.0f) + 1e-6f) * wgt;
  float pr = __shfl_xor(xn, 32, 64);
  float o = xn * cosT[s * 64 + lane] + (lane < 32 ? -pr : pr) * sinT[s * 64 + lane];
  *p = f2bf(o * (isq ? qscale : 1.0f));
}

// -------- V: bf16 QKV v-part (b,s,kvh,d) -> bf16 (b,kvh,d,s) ---------------
__global__ void v_transpose(const u16* __restrict__ QKV, u16* __restrict__ Vt) {
  __shared__ u16 tile[64][72];
  const int s0 = blockIdx.x * 64;
  const int bk = blockIdx.y;
  const int b = bk / KVH_, kvh = bk % KVH_;
  const int t = threadIdx.x;
#pragma unroll
  for (int it = 0; it < 16; it++) {
    int idx = it * 256 + t;
    int sl = idx >> 6, d = idx & 63;
    tile[sl][d] = QKV[(size_t)(b * S_ + s0 + sl) * NQK_ + 2560 + kvh * 64 + d];
  }
  __syncthreads();
#pragma unroll
  for (int it = 0; it < 16; it++) {
    int idx = it * 256 + t;
    int d = idx >> 6, sl = idx & 63;
    Vt[(((size_t)(b * KVH_ + kvh)) * HD_ + d) * S_ + s0 + sl] = tile[sl][d];
  }
}

// ---------------- flash attention, causal GQA, 32x32 MFMA -------------------
// Block = one 64-row q-slab: 4 waves = 2 q-tiles (32 rows) x 2 key-halves.
// Every wave active every kt (uniform loop). End-of-block online-softmax
// merge across key-halves through LDS. 2048 blocks, longest-slab-first.
__global__ __launch_bounds__(256, 4) void attn_fwd(const u16* __restrict__ QKV,
                                                   const u16* __restrict__ Vt,
                                                   u16* __restrict__ Out) {
  __shared__ u16 Ksm[2][64 * 64];   // [key][d], XOR-swizzled 128B rows
  __shared__ u16 Vsm[2][64 * 64];   // [d][key], XOR-swizzled 128B rows

  const int t = threadIdx.x, lane = t & 63, w = t >> 6;
  const int q31 = lane & 31, hi = lane >> 5;
  const int tile_r = w & 1, kside = w >> 1;

  // decode: XCD-aware (2 (b,kvh) panels per XCD) + longest-slab-first
  const int fid = blockIdx.x;                // 0..2047
  const int xcd = fid & 7, slot = fid >> 3;  // 0..255
  const int kg = xcd * 2 + (slot >> 7);      // 0..15
  const int sub = slot & 127;
  const int b = kg >> 3, kvh = kg & 7;
  const int h = kvh * 4 + (sub & 3);
  const int slab = 31 - (sub >> 2);          // 0..31, longest dispatched first

  const int q0 = slab * 64 + tile_r * 32;    // this wave's 32 q-rows
  const int KTM = slab;                      // uniform block loop bound

  const char* Kb = (const char*)(QKV + (size_t)b * S_ * NQK_ + 2048 + kvh * 64);
  const char* Vb = (const char*)(Vt + ((size_t)(b * KVH_ + kvh)) * HD_ * S_);

  // staging (linear LDS dest, inverse-swizzled global source)
  const int SP0 = t * 16, SP1 = 4096 + t * 16;
  const int srow0 = SP0 >> 7, scb0 = (SP0 ^ ((srow0 & 7) << 4)) & 127;
  const int srow1 = SP1 >> 7, scb1 = (SP1 ^ ((srow1 & 7) << 4)) & 127;
  const int SB0 = (w << 10), SB1 = 4096 + (w << 10);
  const size_t KROW = (size_t)NQK_ * 2;

  auto STAGE = [&](int buf, int kt) {
    gload16(Kb + (size_t)(kt * 64 + srow0) * KROW + scb0, (char*)Ksm[buf] + SB0);
    gload16(Kb + (size_t)(kt * 64 + srow1) * KROW + scb1, (char*)Ksm[buf] + SB1);
    gload16(Vb + (size_t)srow0 * (S_ * 2) + (size_t)kt * 128 + scb0, (char*)Vsm[buf] + SB0);
    gload16(Vb + (size_t)srow1 * (S_ * 2) + (size_t)kt * 128 + scb1, (char*)Vsm[buf] + SB1);
  };

  STAGE(0, 0);

  // Q fragments: B-operand, lane = col q; d = sl*16 + hi*8 + j
  bf16x8 qf[4];
  {
    const u16* qp = QKV + (size_t)(b * S_ + q0 + q31) * NQK_ + h * 64 + hi * 8;
#pragma unroll
    for (int sl = 0; sl < 4; sl++) qf[sl] = *(const bf16x8*)(qp + sl * 16);
  }

  f32x16 o0 = {}, o1 = {};
  float m_i = -1e30f, l_i = 0.0f;

  auto cvtpk = [](float a, float bb) {
    u32 r;
    asm("v_cvt_pk_bf16_f32 %0, %1, %2" : "=v"(r) : "v"(a), "v"(bb));
    return r;
  };

  const int swz = (q31 & 7) << 4;
  __syncthreads();
  int cur = 0;

  for (int kt = 0; kt <= KTM; kt++) {
    if (kt < KTM) STAGE(cur ^ 1, kt + 1);

    // wave-uniform skip: (tile0, keys32-63) at diagonal is fully masked
    const bool act = (kt < KTM) || (kside <= tile_r);
    if (act) {
      // QK^T swapped: A = K rows (this wave's 32 keys), B = Q cols
      f32x16 p = {};
      __builtin_amdgcn_s_setprio(1);
#pragma unroll
      for (int sl = 0; sl < 4; sl++) {
        const int byt = ((kside * 32 + q31) * 128 + sl * 32 + hi * 16) ^ swz;
        bf16x8 kf = *(const bf16x8*)((const char*)Ksm[cur] + byt);
        p = __builtin_amdgcn_mfma_f32_32x32x16_bf16(kf, qf[sl], p, 0, 0, 0);
      }
      __builtin_amdgcn_s_setprio(0);

      if (kt == KTM) {  // diagonal: mask local keys > rel
        const int rel = tile_r * 32 + q31 - kside * 32;
#pragma unroll
        for (int r = 0; r < 16; r++) {
          const int crow = (r & 3) + 8 * (r >> 2) + 4 * hi;
          if (crow > rel) p[r] = -1e30f;
        }
      }

      // max: pairwise tree over 16 regs + 1 shfl (other hi-half of keys)
      float a0 = fmaxf(p[0], p[1]),  a1 = fmaxf(p[2], p[3]);
      float a2 = fmaxf(p[4], p[5]),  a3 = fmaxf(p[6], p[7]);
      float a4 = fmaxf(p[8], p[9]),  a5 = fmaxf(p[10], p[11]);
      float a6 = fmaxf(p[12], p[13]), a7 = fmaxf(p[14], p[15]);
      float mx = fmaxf(fmaxf(fmaxf(a0, a1), fmaxf(a2, a3)),
                       fmaxf(fmaxf(a4, a5), fmaxf(a6, a7)));
      mx = fmaxf(mx, __shfl_xor(mx, 32, 64));

      // defer-max (THR=8, log2 domain)
      if (!__all(mx <= m_i + 8.0f)) {
        const float mn = fmaxf(m_i, mx);
        const float al = exp2f(m_i - mn);
        m_i = mn;
        l_i *= al;
#pragma unroll
        for (int r = 0; r < 16; r++) {
          const float aO = __shfl(al, (r & 3) + 8 * (r >> 2) + 4 * hi, 64);
          o0[r] *= aO;
          o1[r] *= aO;
        }
      }

      // P = exp2(s - m); lane-local row-sum
      float rs = 0.0f;
#pragma unroll
      for (int r = 0; r < 16; r++) {
        p[r] = exp2f(p[r] - m_i);
        rs += p[r];
      }
      rs += __shfl_xor(rs, 32, 64);
      l_i += rs;

      // reshape C-layout P -> PV A-fragments (cvt_pk + permlane32_swap)
      bf16x8 pa[2];
      {
        u32 wa, wb2, wc2, wd;
        union { u32x4 u; bf16x8 hh; } cv;
        wa = cvtpk(p[0], p[1]);   wb2 = cvtpk(p[2], p[3]);
        wc2 = cvtpk(p[4], p[5]);  wd = cvtpk(p[6], p[7]);
        asm("v_permlane32_swap_b32 %0, %1" : "+v"(wa), "+v"(wc2));
        asm("v_permlane32_swap_b32 %0, %1" : "+v"(wb2), "+v"(wd));
        cv.u[0] = wa; cv.u[1] = wb2; cv.u[2] = wc2; cv.u[3] = wd; pa[0] = cv.hh;
        wa = cvtpk(p[8], p[9]);    wb2 = cvtpk(p[10], p[11]);
        wc2 = cvtpk(p[12], p[13]); wd = cvtpk(p[14], p[15]);
        asm("v_permlane32_swap_b32 %0, %1" : "+v"(wa), "+v"(wc2));
        asm("v_permlane32_swap_b32 %0, %1" : "+v"(wb2), "+v"(wd));
        cv.u[0] = wa; cv.u[1] = wb2; cv.u[2] = wc2; cv.u[3] = wd; pa[1] = cv.hh;
      }

      // PV: O[q][d] += P[q][k] V[k][d] over this wave's 32 keys
      __builtin_amdgcn_s_setprio(1);
#pragma unroll
      for (int j = 0; j < 2; j++) {
        const int colb = kside * 64 + j * 32 + hi * 16;
        bf16x8 v0 = *(const bf16x8*)((const char*)Vsm[cur] +
                     ((q31 * 128 + colb) ^ swz));
        bf16x8 v1 = *(const bf16x8*)((const char*)Vsm[cur] +
                     (((32 + q31) * 128 + colb) ^ swz));
        o0 = __builtin_amdgcn_mfma_f32_32x32x16_bf16(pa[j], v0, o0, 0, 0, 0);
        o1 = __builtin_amdgcn_mfma_f32_32x32x16_bf16(pa[j], v1, o1, 0, 0, 0);
      }
      __builtin_amdgcn_s_setprio(0);
    }

    __syncthreads();
    cur ^= 1;
  }

  // ---- merge the two key-halves (waves kside=1 publish, kside=0 combine) ---
  float* smo = (float*)Ksm;    // 16 KB = 2 tiles x 64 lanes x 32 f32
  float* smlm = (float*)Vsm;   // l,m per lane
  if (kside == 1) {
    float* dst = smo + tile_r * 2048 + lane * 32;
#pragma unroll
    for (int r = 0; r < 16; r++) { dst[r] = o0[r]; dst[16 + r] = o1[r]; }
    smlm[tile_r * 128 + lane * 2] = l_i;
    smlm[tile_r * 128 + lane * 2 + 1] = m_i;
  }
  __syncthreads();
  if (kside == 0) {
    const float lB = smlm[tile_r * 128 + lane * 2];
    const float mB = smlm[tile_r * 128 + lane * 2 + 1];
    const float m12 = fmaxf(m_i, mB);
    const float aA = exp2f(m_i - m12);
    const float aB = exp2f(mB - m12);
    const float linv = 1.0f / (l_i * aA + lB * aB);
    const float* src = smo + tile_r * 2048 + lane * 32;
#pragma unroll
    for (int r = 0; r < 16; r++) {
      const int crow = (r & 3) + 8 * (r >> 2) + 4 * hi;
      const float fA = __shfl(aA, crow, 64);
      const float fB = __shfl(aB, crow, 64);
      const float fl = __shfl(linv, crow, 64);
      const int qg = q0 + crow;
      u16* op = Out + (((size_t)(b * S_ + qg)) * H_ + h) * HD_;
      op[q31] = f2bf((o0[r] * fA + src[r] * fB) * fl);
      op[32 + q31] = f2bf((o1[r] * fA + src[16 + r] * fB) * fl);
    }
  }
}

// ---------------- host launch ----------------
extern "C" void kernel_launch(void* const* d_in, const int* in_sizes, int n_in,
                              void* d_out, int out_size, void* d_ws, size_t ws_size,
                              hipStream_t stream) {
  const float* x  = (const float*)d_in[0];
  const float* rc = (const float*)d_in[1];
  const float* rs = (const float*)d_in[2];
  const float* Wq = (const float*)d_in[3];
  const float* Wk = (const float*)d_in[4];
  const float* Wv = (const float*)d_in[5];
  const float* Wo = (const float*)d_in[6];
  const float* qw = (const float*)d_in[7];
  const float* kw = (const float*)d_in[8];
  float* out = (float*)d_out;

  char* ws = (char*)d_ws;
  const size_t MB = (size_t)1 << 20;
  u16* xb   = (u16*)(ws + 0 * MB);    // 16 MB bf16 x (reused as attn-out)
  u16* wbq  = (u16*)(ws + 16 * MB);   // 12 MB bf16 [Wq;Wk;Wv] (then Wo reuse)
  u16* QKVb = (u16*)(ws + 28 * MB);   // 24 MB bf16 QKV proj (b,s,3072)
  u16* Vtb  = (u16*)(ws + 52 * MB);   // 4 MB  bf16 V (b,kvh,d,s)
  u16* AO   = xb;

  const int MT = B_ * S_;
  const float QSC = 0.125f * 1.44269504089f;  // (1/sqrt(64)) * log2(e)

  cvt_bf16<<<dim3(MT * DM_ / 1024), 256, 0, stream>>>(x, xb, MT * DM_ / 4);
  cvt_bf16<<<dim3(DM_ * DM_ / 1024), 256, 0, stream>>>(Wq, wbq, DM_ * DM_ / 4);
  cvt_bf16<<<dim3(512 * DM_ / 1024), 256, 0, stream>>>(Wk, wbq + (size_t)DM_ * DM_, 512 * DM_ / 4);
  cvt_bf16<<<dim3(512 * DM_ / 1024), 256, 0, stream>>>(Wv, wbq + (size_t)DM_ * DM_ + (size_t)512 * DM_, 512 * DM_ / 4);

  gemm_btb<<<dim3(NQK_ / BN, MT / BM), 256, 0, stream>>>(xb, wbq, QKVb, MT, NQK_, DM_);

  norm_rope_inplace<<<dim3(MT * 40 / 4), 256, 0, stream>>>(QKVb, rc, rs, qw, kw, QSC);

  v_transpose<<<dim3(S_ / 64, B_ * KVH_), 256, 0, stream>>>(QKVb, Vtb);

  // attention: 2048 blocks (4/CU resident + backfill), key-split waves
  attn_fwd<<<dim3(2048), 256, 0, stream>>>(QKVb, Vtb, AO);

  cvt_bf16<<<dim3(DM_ * DM_ / 1024), 256, 0, stream>>>(Wo, wbq, DM_ * DM_ / 4);
  gemm_bt<<<dim3(DM_ / BN, MT / BM), 256, 0, stream>>>(AO, wbq, out, MT, DM_, DM_);
}